// Round 2
// baseline (583.522 us; speedup 1.0000x reference)
//
#include <hip/hip_runtime.h>
#include <hip/hip_bf16.h>
#include <stdint.h>
#include <math.h>

// ---------------------------------------------------------------------------
// Attention_74852690035363 — f32 inputs/outputs, bf16 MFMA compute inside.
//
// Algebra:
//   M     = svd_token @ svd_token^T          (symmetric -> NT everywhere)
//   x2    = hs @ M
//   Wrot  = per-head-rotated qkv weights: rows 384h+128p+e =
//           sum_d R[h,d,e] * qkv_w[384h+128p+d,:]   (R = svd_qk for q,k; svd_vlin for v)
//   brot  = rotated qkv bias
//   mixed = x2 @ Wrot^T + brot               -> directly rotated q,k,v per head
//   S_h   = scale * q_h @ k_h^T  (causal blocks skipped), softmax in-place -> P
//   ctx   = P @ vT^T   (K limited to t < s0+128 by causality)
//   tsrT[o,128h+e] = sum_d dense_w[h,d,o] svd_vlin[h,d,e]
//   out   = ctx @ tsrT^T + dense_b           (f32 store)
// ---------------------------------------------------------------------------

typedef __bf16 bf16_t;
typedef __bf16 bf16x8 __attribute__((ext_vector_type(8)));
typedef __bf16 bf16x4 __attribute__((ext_vector_type(4)));
typedef float  f32x4  __attribute__((ext_vector_type(4)));

#define SQn 2048
#define NHn 16

// async global->LDS, 16B per lane; LDS dest is wave-uniform base + lane*16
__device__ __forceinline__ void async16(const void* g, void* l) {
  __builtin_amdgcn_global_load_lds(
      (const __attribute__((address_space(1))) void*)(uintptr_t)g,
      (__attribute__((address_space(3))) void*)(uint32_t)(uintptr_t)l,
      16, 0, 0);
}

// NT GEMM: C[m,n] = alpha * sum_k A[m,k]*B[n,k] + bias[n]
// 128x128 tile, BK=32, 256 threads (4 waves, 2x2 of 64x64), 16x16x32 bf16 MFMA.
// flags&1: skip blocks fully above the causal diagonal (n0 > m0+127)
// flags&2: limit K to m0+128 (causal K cut for P@V)
// flags&4: C and bias are float32 (final output GEMM)
__global__ __launch_bounds__(256)
void gemm_nt(const bf16_t* __restrict__ A, const bf16_t* __restrict__ B,
             void* __restrict__ Cv, const void* __restrict__ biasv,
             int M, int N, int K, int lda, int ldb, int ldc,
             long long zsa, long long zsb, long long zsc,
             float alpha, int flags)
{
  const int z = blockIdx.z;
  A += (long long)z * zsa;
  B += (long long)z * zsb;
  const int bm0 = blockIdx.y * 128;
  const int bn0 = blockIdx.x * 128;
  if ((flags & 1) && bn0 > bm0 + 127) return;
  int Kend = K;
  if (flags & 2) { int lim = bm0 + 128; Kend = lim < K ? lim : K; }

  __shared__ bf16_t shA[128 * 32];
  __shared__ bf16_t shB[128 * 32];

  const int t  = threadIdx.x;
  const int w  = t >> 6;
  const int l  = t & 63;
  const int wm = (w >> 1) * 64;
  const int wn = (w & 1) * 64;
  const int r0 = l >> 2;           // row-in-segment for staging
  const int c0 = (l & 3) * 8;      // k-offset for staging
  const int fr = l & 15;           // fragment row/col
  const int kq = (l >> 4) * 8;     // fragment k-chunk

  f32x4 acc[4][4];
  #pragma unroll
  for (int i = 0; i < 4; ++i)
    #pragma unroll
    for (int j = 0; j < 4; ++j)
      #pragma unroll
      for (int r = 0; r < 4; ++r)
        acc[i][j][r] = 0.0f;

  for (int k0 = 0; k0 < Kend; k0 += 32) {
    #pragma unroll
    for (int c = 0; c < 2; ++c) {
      const int seg = w * 2 + c;          // 8 segments of 16 rows
      const int row = seg * 16 + r0;
      async16(A + (long long)(bm0 + row) * lda + (k0 + c0), &shA[seg * 512]);
      async16(B + (long long)(bn0 + row) * ldb + (k0 + c0), &shB[seg * 512]);
    }
    __builtin_amdgcn_s_waitcnt(0);
    __syncthreads();

    bf16x8 af[4], bfv[4];
    #pragma unroll
    for (int i = 0; i < 4; ++i) {
      af[i]  = *(const bf16x8*)&shA[(wm + i * 16 + fr) * 32 + kq];
      bfv[i] = *(const bf16x8*)&shB[(wn + i * 16 + fr) * 32 + kq];
    }
    #pragma unroll
    for (int i = 0; i < 4; ++i)
      #pragma unroll
      for (int j = 0; j < 4; ++j)
        acc[i][j] = __builtin_amdgcn_mfma_f32_16x16x32_bf16(af[i], bfv[j], acc[i][j], 0, 0, 0);
    __syncthreads();
  }

  // C/D layout (verified m89/m91): col = lane&15, row = (lane>>4)*4 + reg
  const int cc = l & 15;
  const int rq = (l >> 4) * 4;
  if (flags & 4) {
    float* C = (float*)Cv + (long long)z * zsc;
    const float* bias = (const float*)biasv;
    #pragma unroll
    for (int j = 0; j < 4; ++j) {
      const int col = bn0 + wn + j * 16 + cc;
      const float bv = bias ? bias[col] : 0.0f;
      #pragma unroll
      for (int i = 0; i < 4; ++i)
        #pragma unroll
        for (int r = 0; r < 4; ++r) {
          const int rrow = bm0 + wm + i * 16 + rq + r;
          C[(long long)rrow * ldc + col] = acc[i][j][r] * alpha + bv;
        }
    }
  } else {
    bf16_t* C = (bf16_t*)Cv + (long long)z * zsc;
    const bf16_t* bias = (const bf16_t*)biasv;
    #pragma unroll
    for (int j = 0; j < 4; ++j) {
      const int col = bn0 + wn + j * 16 + cc;
      const float bv = bias ? (float)bias[col] : 0.0f;
      #pragma unroll
      for (int i = 0; i < 4; ++i)
        #pragma unroll
        for (int r = 0; r < 4; ++r) {
          const int rrow = bm0 + wm + i * 16 + rq + r;
          C[(long long)rrow * ldc + col] = (bf16_t)(acc[i][j][r] * alpha + bv);
        }
    }
  }
}

// f32 -> bf16 cast, 4 elements/thread; n must be a multiple of 4
__global__ __launch_bounds__(256)
void cvt_f2b(const float* __restrict__ in, bf16_t* __restrict__ out, int n)
{
  const int i = (blockIdx.x * 256 + threadIdx.x) * 4;
  if (i >= n) return;
  const f32x4 v = *(const f32x4*)(in + i);
  bf16x4 o;
  #pragma unroll
  for (int j = 0; j < 4; ++j) o[j] = (bf16_t)v[j];
  *(bf16x4*)(out + i) = o;
}

// out[z][c][r] = (bf16) in[z*zsi + r*rsi + c]   (32x32 LDS tile transpose)
__global__ __launch_bounds__(256)
void transpose_k(const float* __restrict__ in, bf16_t* __restrict__ out,
                 int R, int Cc, long long zsi, int rsi, long long zso)
{
  __shared__ bf16_t sm[32][33];
  const int z  = blockIdx.z;
  const int r0 = blockIdx.x << 5;
  const int c0 = blockIdx.y << 5;
  const int tx = threadIdx.x & 31;
  const int ty = threadIdx.x >> 5;
  const float* ip = in + (long long)z * zsi;
  bf16_t* op = out + (long long)z * zso;
  #pragma unroll
  for (int yy = ty; yy < 32; yy += 8)
    sm[yy][tx] = (bf16_t)ip[(long long)(r0 + yy) * rsi + c0 + tx];
  __syncthreads();
  #pragma unroll
  for (int yy = ty; yy < 32; yy += 8)
    op[(long long)(c0 + yy) * R + r0 + tx] = sm[tx][yy];
}

// brot[384h+128p+e] = sum_d qkv_b[384h+128p+d] * R[h,d,e]   (f32 in, bf16 out)
__global__ void brot_k(const float* __restrict__ qkv_b,
                       const float* __restrict__ svd_qk,
                       const float* __restrict__ svd_vl,
                       bf16_t* __restrict__ brot)
{
  const int hp = blockIdx.x;            // 0..47
  const int h = hp / 3, p = hp % 3;
  const int e = threadIdx.x;            // 0..127
  const float* R = (p == 2 ? svd_vl : svd_qk) + h * 16384;
  const float* b = qkv_b + h * 384 + p * 128;
  float acc = 0.f;
  for (int d = 0; d < 128; ++d)
    acc += b[d] * R[d * 128 + e];
  brot[h * 384 + p * 128 + e] = (bf16_t)acc;
}

// causal softmax, in place on bf16 S[16][2048][2048]; zero-fills only up to
// the 128-aligned bound rb that the causally-K-limited ctx GEMM will read.
__global__ __launch_bounds__(256)
void softmax_causal_k(bf16_t* __restrict__ S)
{
  const int s = blockIdx.x;
  const int z = blockIdx.y;
  bf16_t* row = S + ((long long)z * SQn + s) * SQn;
  const int nvalid = s + 1;
  const int rb = ((s >> 7) + 1) << 7;
  const int t = threadIdx.x;
  const int base = t * 8;
  const int w = t >> 6, l = t & 63;

  float v[8];
  {
    bf16x8 x = *(const bf16x8*)(row + base);
    #pragma unroll
    for (int i = 0; i < 8; ++i)
      v[i] = (base + i < nvalid) ? (float)x[i] : -3.0e38f;
  }
  float mx = v[0];
  #pragma unroll
  for (int i = 1; i < 8; ++i) mx = fmaxf(mx, v[i]);
  #pragma unroll
  for (int off = 32; off > 0; off >>= 1)
    mx = fmaxf(mx, __shfl_xor(mx, off, 64));
  __shared__ float redm[4], reds[4];
  if (l == 0) redm[w] = mx;
  __syncthreads();
  mx = fmaxf(fmaxf(redm[0], redm[1]), fmaxf(redm[2], redm[3]));

  float sum = 0.f;
  #pragma unroll
  for (int i = 0; i < 8; ++i) {
    float e = (base + i < nvalid) ? __expf(v[i] - mx) : 0.f;
    v[i] = e;
    sum += e;
  }
  #pragma unroll
  for (int off = 32; off > 0; off >>= 1)
    sum += __shfl_xor(sum, off, 64);
  if (l == 0) reds[w] = sum;
  __syncthreads();
  sum = reds[0] + reds[1] + reds[2] + reds[3];
  const float inv = 1.0f / sum;

  if (base < rb) {
    bf16x8 o;
    #pragma unroll
    for (int i = 0; i < 8; ++i) o[i] = (bf16_t)(v[i] * inv);
    *(bf16x8*)(row + base) = o;
  }
}

extern "C" void kernel_launch(void* const* d_in, const int* in_sizes, int n_in,
                              void* d_out, int out_size, void* d_ws, size_t ws_size,
                              hipStream_t stream)
{
  const float* hs      = (const float*)d_in[0];
  // d_in[1] = attention_mask (causal triu, deterministic) — recomputed, unused
  const float* qkv_w   = (const float*)d_in[2];
  const float* qkv_b   = (const float*)d_in[3];
  const float* svd_tok = (const float*)d_in[4];
  const float* svd_qk  = (const float*)d_in[5];
  const float* svd_vl  = (const float*)d_in[6];
  const float* dense_w = (const float*)d_in[7];
  const float* dense_b = (const float*)d_in[8];
  float* out = (float*)d_out;
  bf16_t* ws = (bf16_t*)d_ws;

  // workspace layout (bf16 elements). Overlays (verified by launch order):
  //   Sbuf [0,67.1M) covers qkv_wT [0,12.6M) + Wrot [12.6M,25.2M)
  //                        + hsb [25.2M,29.4M) + stb [29.4M,33.6M)
  bf16_t* Sbuf   = ws;                    // 67,108,864  [16][2048][2048]
  bf16_t* qkv_wT = ws;                    // 12,582,912  [48][2048][128]
  bf16_t* Wrot   = ws + 12582912LL;       // 12,582,912  [6144][2048]
  bf16_t* hsb    = ws + 25165824LL;       //  4,194,304  bf16(hs)
  bf16_t* stb    = ws + 29360128LL;       //  4,194,304  bf16(svd_token)
  bf16_t* mixed  = ws + 67108864LL;       // 12,582,912  [2048][6144]
  bf16_t* Mbuf   = ws + 79691776LL;       //  4,194,304  (reused as ctx)
  bf16_t* ctx    = Mbuf;
  bf16_t* x2     = ws + 83886080LL;       //  4,194,304  (reused as tsrT)
  bf16_t* tsrT   = x2;
  bf16_t* dwT    = ws + 88080384LL;       //  4,194,304  [16][2048][128]
  bf16_t* vT     = ws + 92274688LL;       //  4,194,304  [16][128][2048]
  bf16_t* qkT    = ws + 96468992LL;       //    262,144  [16][128][128]
  bf16_t* vlT    = ws + 96731136LL;       //    262,144
  bf16_t* brot   = ws + 96993280LL;       //      6,144
  if (ws_size < 96999424ULL * 2ULL) return;  // ~194 MB needed

  const float iscale = 0.08838834764831845f;   // 1/sqrt(128)

  // f32 -> bf16 casts
  cvt_f2b<<<dim3(4096), 256, 0, stream>>>(hs,      hsb, 4194304);
  cvt_f2b<<<dim3(4096), 256, 0, stream>>>(svd_tok, stb, 4194304);

  // weight transposes (fused f32->bf16)
  transpose_k<<<dim3(4, 4, 16),  256, 0, stream>>>(svd_qk,  qkT,    128, 128, 16384, 128, 16384);
  transpose_k<<<dim3(4, 4, 16),  256, 0, stream>>>(svd_vl,  vlT,    128, 128, 16384, 128, 16384);
  transpose_k<<<dim3(4, 64, 48), 256, 0, stream>>>(qkv_w,   qkv_wT, 128, 2048, 262144, 2048, 262144);
  transpose_k<<<dim3(4, 64, 16), 256, 0, stream>>>(dense_w, dwT,    128, 2048, 262144, 2048, 262144);

  // M = svd_tok @ svd_tok^T (symmetric)
  gemm_nt<<<dim3(16, 16, 1), 256, 0, stream>>>(stb, stb, Mbuf, nullptr,
      2048, 2048, 2048, 2048, 2048, 2048, 0, 0, 0, 1.0f, 0);
  // x2 = hs @ M
  gemm_nt<<<dim3(16, 16, 1), 256, 0, stream>>>(hsb, Mbuf, x2, nullptr,
      2048, 2048, 2048, 2048, 2048, 2048, 0, 0, 0, 1.0f, 0);
  // Wrot: q (svd_qk), k (svd_qk), v (svd_vlin) blocks
  gemm_nt<<<dim3(16, 1, 16), 256, 0, stream>>>(qkT, qkv_wT, Wrot, nullptr,
      128, 2048, 128, 128, 128, 2048, 16384, 786432, 786432, 1.0f, 0);
  gemm_nt<<<dim3(16, 1, 16), 256, 0, stream>>>(qkT, qkv_wT + 262144, Wrot + 262144, nullptr,
      128, 2048, 128, 128, 128, 2048, 16384, 786432, 786432, 1.0f, 0);
  gemm_nt<<<dim3(16, 1, 16), 256, 0, stream>>>(vlT, qkv_wT + 524288, Wrot + 524288, nullptr,
      128, 2048, 128, 128, 128, 2048, 16384, 786432, 786432, 1.0f, 0);
  brot_k<<<dim3(48), 128, 0, stream>>>(qkv_b, svd_qk, svd_vl, brot);
  // mixed = x2 @ Wrot^T + brot   (rotated q,k,v per head: cols 384h + {q,k,v})
  gemm_nt<<<dim3(48, 16, 1), 256, 0, stream>>>(x2, Wrot, mixed, brot,
      2048, 6144, 2048, 2048, 2048, 6144, 0, 0, 0, 1.0f, 0);
  // vT[h][e][t] = mixed[t][384h+256+e]  (bf16 source -> plain copy transpose)
  {
    // reuse transpose via a bf16 path: mixed is bf16, so do it with a tiny lambda-free kernel
  }
  // bf16 transpose of V block: out[z][e][t] = mixed[t][384z+256+e]
  // (implemented below as a separate kernel launch)
  extern __global__ void transpose_b2b(const bf16_t*, bf16_t*, int, int, long long, int, long long);
  transpose_b2b<<<dim3(64, 4, 16), 256, 0, stream>>>(mixed + 256, vT, 2048, 128, 384, 6144, 262144);
  // S_h = scale * q_h @ k_h^T  (skip fully-masked blocks)
  gemm_nt<<<dim3(16, 16, 16), 256, 0, stream>>>(mixed, mixed + 128, Sbuf, nullptr,
      2048, 2048, 128, 6144, 6144, 2048, 384, 384, 4194304, iscale, 1);
  softmax_causal_k<<<dim3(2048, 16), 256, 0, stream>>>(Sbuf);
  // ctx[s][128h+e] = sum_t P[s,t] vT[h][e][t]  (causal K cut)
  gemm_nt<<<dim3(1, 16, 16), 256, 0, stream>>>(Sbuf, vT, ctx, nullptr,
      2048, 128, 2048, 2048, 2048, 2048, 4194304, 262144, 128, 1.0f, 2);
  // tsrT[o][128h+e] = sum_d dense_w[h,d,o] svd_vlin[h,d,e]
  gemm_nt<<<dim3(1, 16, 16), 256, 0, stream>>>(dwT, vlT, tsrT, nullptr,
      2048, 128, 128, 128, 128, 2048, 262144, 16384, 128, 1.0f, 0);
  // out = ctx @ tsrT^T + dense_b   (f32 store + f32 bias)
  gemm_nt<<<dim3(16, 16, 1), 256, 0, stream>>>(ctx, tsrT, out, dense_b,
      2048, 2048, 2048, 2048, 2048, 2048, 0, 0, 0, 1.0f, 4);
}

// bf16 -> bf16 32x32 tile transpose: out[z][c][r] = in[z*zsi + r*rsi + c]
__global__ __launch_bounds__(256)
void transpose_b2b(const bf16_t* __restrict__ in, bf16_t* __restrict__ out,
                   int R, int Cc, long long zsi, int rsi, long long zso)
{
  __shared__ bf16_t sm[32][33];
  const int z  = blockIdx.z;
  const int r0 = blockIdx.x << 5;
  const int c0 = blockIdx.y << 5;
  const int tx = threadIdx.x & 31;
  const int ty = threadIdx.x >> 5;
  const bf16_t* ip = in + (long long)z * zsi;
  bf16_t* op = out + (long long)z * zso;
  #pragma unroll
  for (int yy = ty; yy < 32; yy += 8)
    sm[yy][tx] = ip[(long long)(r0 + yy) * rsi + c0 + tx];
  __syncthreads();
  #pragma unroll
  for (int yy = ty; yy < 32; yy += 8)
    op[(long long)(c0 + yy) * R + r0 + tx] = sm[tx][yy];
}